// Round 7
// baseline (40.760 us; speedup 1.0000x reference)
//
#include <hip/hip_runtime.h>

// arDCA: out[n,q] = softmax_q( h[400,q] + sum_{j<400} J[400,q,j,tok(n,j)] )
// R7: two kernels. K0: Jq2[j][t][q] transpose (705 KB, L2-resident).
// K1: block = 3 n-rows x ALL 400 j, 10 async double-buffered stages of 40 j.
//     Long HBM segments (3360 B/row/stage), counted vmcnt, 2 barriers/stage,
//     waves split j 4-ways in gather, in-block softmax -> out. No partials.
// N=4096, RES=400, Q=21, L=512.

#define QA      21
#define RESI    400
#define NSEQ    4096
#define ROWS    3                // n-rows per block
#define SJ      40               // j per stage
#define NST     10               // stages (400 j)
#define STAGE_F (ROWS*SJ*QA)     // 2520 floats (10080 B)
#define STAGE_V4 (STAGE_F/4)     // 630 dwordx4
#define NBX     1366             // ceil(4096/3)
#define JQ2_ELEMS (RESI*QA*QA)   // 176400

#define GLOAD_LDS16(g, l)                                                     \
    __builtin_amdgcn_global_load_lds(                                         \
        (const __attribute__((address_space(1))) void*)(g),                   \
        (__attribute__((address_space(3))) void*)(l), 16, 0, 0)

// ---------------- K0: Jq2[(j*21+a)*21+q] = J[((8400+q)*512+j)*21+a] --------
__global__ __launch_bounds__(256) void k0_jq2(const float* __restrict__ J,
                                              float* __restrict__ Jq2) {
    int s = blockIdx.x * 256 + threadIdx.x;
    if (s >= JQ2_ELEMS) return;
    int q  = s / 8400;            // 0..20
    int ja = s - q * 8400;        // j*21+a, contiguous -> coalesced read
    Jq2[ja * 21 + q] = J[(8400 + q) * 10752 + ja];
}

// ---------------- K1: fully fused, long-segment staging --------------------
__global__ __launch_bounds__(256) void k1_main(const float* __restrict__ X,
                                               const float* __restrict__ Jq2,
                                               const float* __restrict__ h,
                                               float* __restrict__ out) {
    __shared__ float buf[2][STAGE_F];     // 20160 B
    __shared__ int   tokb[2][ROWS * SJ];  // 2x120 ints
    __shared__ float comb[4][63];
    __shared__ float lg[63];

    const int tid = threadIdx.x;
    const int w   = tid >> 6, l = tid & 63;
    const int n0  = blockIdx.x * ROWS;

    // per-lane prefetch mapping: chunk e = tid + k*256 of 630 dwordx4.
    // stage bytes per row: 3360 (210 x16B); rows at stride 33600 B.
    const char* Xb = (const char*)X;
    const char* pbase[3];
    bool pv[3];
    #pragma unroll
    for (int k = 0; k < 3; ++k) {
        int e   = tid + (k << 8);
        pv[k]   = (e < STAGE_V4);
        int row = e / 210;
        int col = e - row * 210;
        int nr  = n0 + row; if (nr > NSEQ - 1) nr = NSEQ - 1;   // tail clamp
        pbase[k] = Xb + (size_t)nr * 33600 + (size_t)col * 16;
    }

    const int  q   = l % 21;
    const int  ns  = l / 21;              // 0..2 valid
    const bool act = (l < 63);

    auto issue = [&](int s) {
        char* dst = (char*)&buf[s & 1][0];
        #pragma unroll
        for (int k = 0; k < 3; ++k)
            if (pv[k])
                GLOAD_LDS16(pbase[k] + s * 3360, dst + ((tid + (k << 8)) << 4));
    };

    issue(0);
    float acc = 0.f;

    #pragma unroll 2
    for (int s = 0; s < NST; ++s) {
        const int p = s & 1;
        if (s + 1 < NST) {
            issue(s + 1);
            // waves 0/1 issue 3 glds/stage, waves 2/3 issue 2 -> counted wait
            if (w < 2) asm volatile("s_waitcnt vmcnt(3)" ::: "memory");
            else       asm volatile("s_waitcnt vmcnt(2)" ::: "memory");
        } else {
            asm volatile("s_waitcnt vmcnt(0)" ::: "memory");
        }
        __builtin_amdgcn_s_barrier();
        __builtin_amdgcn_sched_barrier(0);

        // tokenize: 120 cells, one per thread; iota-dot exact for one-hot
        if (tid < ROWS * SJ) {
            const float* cell = &buf[p][tid * QA];
            float fa = 0.f;
            #pragma unroll
            for (int a = 0; a < QA; ++a) fa = fmaf(cell[a], (float)a, fa);
            tokb[p][tid] = (int)(fa + 0.5f);
        }
        asm volatile("s_waitcnt lgkmcnt(0)" ::: "memory");
        __builtin_amdgcn_s_barrier();
        __builtin_amdgcn_sched_barrier(0);

        // gather: wave w owns 10 j of this stage; lanes = 21q x 3n;
        // per j: 3 runs of 84B from L2-hot Jq2, tok reads broadcast
        if (act) {
            const int jb = s * SJ + w * 10;
            const int* tp = &tokb[p][ns * SJ + w * 10];
            #pragma unroll
            for (int jj = 0; jj < 10; ++jj) {
                int t = tp[jj];
                acc += Jq2[(jb + jj) * 441 + t * 21 + q];
            }
        }
    }

    // cross-wave combine + softmax + coalesced out
    if (act) comb[w][l] = acc;
    __syncthreads();
    if (tid < 63)
        lg[tid] = comb[0][tid] + comb[1][tid] + comb[2][tid] + comb[3][tid]
                + h[8400 + tid % 21];
    __syncthreads();
    if (tid < 63) {
        const int nn = n0 + ns;
        if (nn < NSEQ) {
            const float* r = lg + ns * 21;
            float m = -1e30f;
            #pragma unroll
            for (int a = 0; a < QA; ++a) m = fmaxf(m, r[a]);
            float den = 0.f;
            #pragma unroll
            for (int a = 0; a < QA; ++a) den += __expf(r[a] - m);
            out[nn * QA + q] = __expf(r[q] - m) / den;
        }
    }
}

extern "C" void kernel_launch(void* const* d_in, const int* in_sizes, int n_in,
                              void* d_out, int out_size, void* d_ws, size_t ws_size,
                              hipStream_t stream) {
    const float* X = (const float*)d_in[0];   // [4096,400,21] one-hot
    const float* h = (const float*)d_in[1];   // [512,21]
    const float* J = (const float*)d_in[2];   // [512,21,512,21]
    float* out = (float*)d_out;               // [4096,21]

    float* Jq2 = (float*)d_ws;                // 176400 floats (~706 KB)

    k0_jq2<<<(JQ2_ELEMS + 255) / 256, 256, 0, stream>>>(J, Jq2);
    k1_main<<<NBX, 256, 0, stream>>>(X, Jq2, h, out);
}